// Round 10
// baseline (762.560 us; speedup 1.0000x reference)
//
#include <hip/hip_runtime.h>
#include <math.h>

#define NB 4
#define T 65536
#define TIN 8192
#define LL 256
#define KCL 6144   // per-layer kernel channels = 32*64*3

__device__ __forceinline__ float lrelu_f(float v) { return v >= 0.f ? v : 0.2f * v; }

// ---------------- phase1: convt (264 blocks) + trunk (32 blocks) merged ----------------
union __align__(16) Phase1LDS {
    struct { float xs[32][264]; float wm[64][128]; } cvt;   // 65.8 KB
    struct { float hs[64][68]; float xsp[20][68]; } trk;    // 22.8 KB
};

__global__ void __launch_bounds__(512) phase1(
    const float* __restrict__ x, const float* __restrict__ cw,
    const float* __restrict__ cbias, float* __restrict__ hout,
    const float* __restrict__ spec,
    const float* __restrict__ kp_in_w, const float* __restrict__ kp_in_b,
    const float* __restrict__ rb_w1, const float* __restrict__ rb_b1,
    const float* __restrict__ rb_w2, const float* __restrict__ rb_b2,
    float* __restrict__ kp_h) {
    __shared__ Phase1LDS u;
    const int bid = blockIdx.x;
    const int tid = threadIdx.x;
    const int lane = tid & 63, wv = tid >> 6;

    if (bid < 264) {
        // ================= convt role (unchanged) =================
        const int bx = bid % 33;
        const int rr = bid / 33;
        const int mtp = rr & 1;
        const int b = rr >> 1;
        const int s0base = bx * 256;
        float (*xs)[264] = u.cvt.xs;
        float (*wm)[128] = u.cvt.wm;

        const float* xb = x + (size_t)b * 32 * TIN;
        for (int idx = tid; idx < 32 * 64; idx += 512) {
            int c = idx >> 6, q = idx & 63;
            int p = s0base + q * 4;
            float4 v = (p + 3 < TIN) ? *(const float4*)(xb + c * TIN + p)
                                     : make_float4(0.f, 0.f, 0.f, 0.f);
            *(float4*)&xs[c][4 + 4 * q] = v;
        }
        if (tid < 32) {
            int p = s0base - 1;
            xs[tid][3] = (p >= 0) ? xb[tid * TIN + p] : 0.f;
        }
        for (int idx = tid; idx < 8192; idx += 512) {
            int i = idx >> 7, mm = idx & 127;
            int oo = mtp * 16 + (mm >> 3), k0 = mm & 7;
            wm[i][mm] = (i < 32) ? cw[i * 512 + oo * 16 + k0]
                                 : cw[(i - 32) * 512 + oo * 16 + k0 + 8];
        }
        __syncthreads();

        float acc[2][8][4];
#pragma unroll
        for (int ol = 0; ol < 2; ++ol) {
            float bo = cbias[mtp * 16 + wv * 2 + ol];
#pragma unroll
            for (int k0 = 0; k0 < 8; ++k0)
#pragma unroll
                for (int si = 0; si < 4; ++si) acc[ol][k0][si] = bo;
        }

        for (int c = 0; c < 32; ++c) {
            float xm1[4], x0[4];
#pragma unroll
            for (int si = 0; si < 4; ++si) {
                xm1[si] = xs[c][lane + si * 64 + 3];
                x0[si]  = xs[c][lane + si * 64 + 4];
            }
            float w0[16], w1[16];
#pragma unroll
            for (int q = 0; q < 4; ++q) {
                *(float4*)&w0[q * 4] = *(const float4*)&wm[c][wv * 16 + q * 4];
                *(float4*)&w1[q * 4] = *(const float4*)&wm[32 + c][wv * 16 + q * 4];
            }
#pragma unroll
            for (int ol = 0; ol < 2; ++ol)
#pragma unroll
                for (int k0 = 0; k0 < 8; ++k0)
#pragma unroll
                    for (int si = 0; si < 4; ++si)
                        acc[ol][k0][si] += x0[si] * w0[ol * 8 + k0] + xm1[si] * w1[ol * 8 + k0];
        }

#pragma unroll
        for (int ol = 0; ol < 2; ++ol) {
            float* ob = hout + ((size_t)b * 32 + mtp * 16 + wv * 2 + ol) * T;
#pragma unroll
            for (int si = 0; si < 4; ++si) {
                int tb = (s0base + lane + si * 64) * 8 - 4;
                if (tb >= 0 && tb < T)
                    *(float4*)(ob + tb) = make_float4(acc[ol][0][si], acc[ol][1][si],
                                                      acc[ol][2][si], acc[ol][3][si]);
                if (tb + 4 >= 0 && tb + 4 < T)
                    *(float4*)(ob + tb + 4) = make_float4(acc[ol][4][si], acc[ol][5][si],
                                                          acc[ol][6][si], acc[ol][7][si]);
            }
        }
        return;
    }

    // ================= trunk role: lane = oc, weights in VGPRs =================
    const int tb2 = bid - 264;
    const int lq = tb2 & 7, b = tb2 >> 3;
    const int oc = lane;            // lane = output channel (64)
    const int j0 = wv * 8;          // wave's 8 window cols (waves 6,7 idle)
    const int l0 = lq * 32;
    const bool active = (j0 < 48);

    float (*hs)[68] = u.trk.hs;     // hs[c][2 + j] = window col j; 16B-aligned rows
    float (*xsp)[68] = u.trk.xsp;   // xsp[c][4 + jj] = spec window col jj

    for (int idx = tid; idx < 64 * 68; idx += 512) ((float*)hs)[idx] = 0.f;

    // ---- kp_in: K=5, pad=2, Cin=100 in 5 chunks of 20; out j in [2,48) ----
    float acc[8];
#pragma unroll
    for (int q = 0; q < 8; ++q) acc[q] = kp_in_b[oc];

    for (int cc = 0; cc < 5; ++cc) {
        __syncthreads();
        for (int idx = tid; idx < 20 * 68; idx += 512) {
            int c = idx / 68, v = idx - c * 68;
            int jj = v - 4;
            int l = l0 - 9 + jj;
            float val = 0.f;
            if (jj >= 0 && jj < 56 && l >= 0 && l < 256)
                val = spec[((size_t)b * 100 + cc * 20 + c) * LL + l];
            xsp[c][v] = val;
        }
        __syncthreads();
        if (active) {
#pragma unroll
            for (int half = 0; half < 2; ++half) {
                const int c0 = half ? 12 : 0;
                const int nc = half ? 8 : 12;
                float wreg[60];
                const float* wp = kp_in_w + (size_t)oc * 500 + cc * 100 + c0 * 5;
#pragma unroll
                for (int q4 = 0; q4 < 15; ++q4)
                    if (q4 * 4 < nc * 5)
                        *(float4*)&wreg[q4 * 4] = *(const float4*)(wp + q4 * 4);
#pragma unroll
                for (int c = 0; c < nc; ++c) {
                    float xw[16];
                    *(float4*)&xw[0]  = *(const float4*)&xsp[c0 + c][j0];
                    *(float4*)&xw[4]  = *(const float4*)&xsp[c0 + c][j0 + 4];
                    *(float4*)&xw[8]  = *(const float4*)&xsp[c0 + c][j0 + 8];
                    *(float4*)&xw[12] = *(const float4*)&xsp[c0 + c][j0 + 12];
#pragma unroll
                    for (int q = 0; q < 8; ++q)
#pragma unroll
                        for (int k = 0; k < 5; ++k)
                            acc[q] += wreg[c * 5 + k] * xw[q + k + 2];
                }
            }
        }
        __syncthreads();
    }
    if (active) {
#pragma unroll
        for (int q = 0; q < 8; ++q) {
            int j = j0 + q;
            if (j >= 2 && j < 48) {
                int labs = l0 - 9 + j;
                hs[oc][2 + j] = (labs >= 0 && labs < 256) ? acc[q] : 0.f;
            }
        }
    }
    __syncthreads();

    // ---- 3 residual blocks (Cin=64, K=3) ----
    for (int i = 0; i < 3; ++i) {
        const int jlo1 = 3 + 2 * i, jhi1 = 47 - 2 * i;
        const int jlo2 = jlo1 + 1, jhi2 = jhi1 - 1;
        float r[8], a1[8];
        if (active) {
#pragma unroll
            for (int q = 0; q < 8; ++q) {
                a1[q] = rb_b1[i * 64 + oc];
                r[q]  = hs[oc][2 + j0 + q];
            }
#pragma unroll
            for (int half = 0; half < 2; ++half) {
                float wreg[96];
                const float* wp = rb_w1 + (size_t)i * 12288 + (size_t)oc * 192 + half * 96;
#pragma unroll
                for (int q4 = 0; q4 < 24; ++q4)
                    *(float4*)&wreg[q4 * 4] = *(const float4*)(wp + q4 * 4);
#pragma unroll
                for (int c = 0; c < 32; ++c) {
                    const int cg = half * 32 + c;
                    float xw[12];
                    *(float4*)&xw[0] = *(const float4*)&hs[cg][j0];
                    *(float4*)&xw[4] = *(const float4*)&hs[cg][j0 + 4];
                    *(float4*)&xw[8] = *(const float4*)&hs[cg][j0 + 8];
#pragma unroll
                    for (int q = 0; q < 8; ++q)
#pragma unroll
                        for (int k = 0; k < 3; ++k)
                            a1[q] += wreg[c * 3 + k] * xw[q + k + 1];
                }
            }
        }
        __syncthreads();
        if (active) {
#pragma unroll
            for (int q = 0; q < 8; ++q) {
                int j = j0 + q;
                if (j >= jlo1 && j < jhi1) {
                    int labs = l0 - 9 + j;
                    hs[oc][2 + j] = (labs >= 0 && labs < 256) ? lrelu_f(a1[q]) : 0.f;
                }
            }
        }
        __syncthreads();
        float a2[8];
        if (active) {
#pragma unroll
            for (int q = 0; q < 8; ++q) a2[q] = rb_b2[i * 64 + oc];
#pragma unroll
            for (int half = 0; half < 2; ++half) {
                float wreg[96];
                const float* wp = rb_w2 + (size_t)i * 12288 + (size_t)oc * 192 + half * 96;
#pragma unroll
                for (int q4 = 0; q4 < 24; ++q4)
                    *(float4*)&wreg[q4 * 4] = *(const float4*)(wp + q4 * 4);
#pragma unroll
                for (int c = 0; c < 32; ++c) {
                    const int cg = half * 32 + c;
                    float xw[12];
                    *(float4*)&xw[0] = *(const float4*)&hs[cg][j0];
                    *(float4*)&xw[4] = *(const float4*)&hs[cg][j0 + 4];
                    *(float4*)&xw[8] = *(const float4*)&hs[cg][j0 + 8];
#pragma unroll
                    for (int q = 0; q < 8; ++q)
#pragma unroll
                        for (int k = 0; k < 3; ++k)
                            a2[q] += wreg[c * 3 + k] * xw[q + k + 1];
                }
            }
        }
        __syncthreads();
        if (active) {
#pragma unroll
            for (int q = 0; q < 8; ++q) {
                int j = j0 + q;
                if (j >= jlo2 && j < jhi2) {
                    int labs = l0 - 9 + j;
                    hs[oc][2 + j] = (labs >= 0 && labs < 256) ? (lrelu_f(a2[q]) + r[q]) : 0.f;
                }
            }
        }
        __syncthreads();
    }

    // ---- write kp_h (central 32 cols = window cols 9..40 -> hs col 11..42) ----
    for (int idx = tid; idx < 2048; idx += 512) {
        int c = idx >> 5, jj = idx & 31;
        kp_h[((size_t)b * 64 + c) * LL + l0 + jj] = hs[c][11 + jj];
    }
}

// ---------------- kern head GEMM (+ bias head blocks at bx>=192 on layer 0) ----------------
__global__ void __launch_bounds__(256, 3) kern_head(const float* __restrict__ kp_h,
                                                    const float* __restrict__ kw,
                                                    const float* __restrict__ kb,
                                                    const float* __restrict__ bias_w,
                                                    const float* __restrict__ bias_b,
                                                    float* __restrict__ kh,
                                                    float* __restrict__ bh, int layer) {
    const int bx = blockIdx.x, b = blockIdx.y;
    const bool isbias = (bx >= 192);
    const int tid = threadIdx.x, lane = tid & 63, wv = tid >> 6;
    __shared__ float xs[32][264];
    __shared__ float ws[96][36];

    int g = 0, oc0 = 0, ci = 0, kk = 0, ocb0 = 0;
    const float* wsrc;
    size_t wrow0;
    int wstride;
    if (!isbias) {
        g = bx >> 1; oc0 = (bx & 1) * 32;
        ci = g / 3; kk = g - ci * 3;
        wsrc = kw + (size_t)layer * KCL * 192;
        wrow0 = (size_t)((ci * 64 + oc0) * 3 + kk) * 192;
        wstride = 576;
    } else {
        ocb0 = (bx - 192) * 32;
        wsrc = bias_w;
        wrow0 = (size_t)ocb0 * 192;
        wstride = 192;
    }

    float acc[8][4];
#pragma unroll
    for (int oi = 0; oi < 8; ++oi) {
        float bv = isbias ? bias_b[ocb0 + wv * 8 + oi]
                          : kb[layer * KCL + (ci * 64 + oc0 + wv * 8 + oi) * 3 + kk];
#pragma unroll
        for (int si = 0; si < 4; ++si) acc[oi][si] = bv;
    }

    for (int half = 0; half < 2; ++half) {
        const int hc0 = half * 32;
        __syncthreads();
        for (int idx = tid; idx < 32 * 64; idx += 256) {
            int c = idx >> 6, q = idx & 63;
            *(float4*)&xs[c][4 + 4 * q] =
                *(const float4*)(kp_h + ((size_t)b * 64 + hc0 + c) * LL + 4 * q);
        }
        if (tid < 32) { xs[tid][3] = 0.f; xs[tid][260] = 0.f; }
        for (int idx = tid; idx < 3072; idx += 256) {
            int ocl = idx / 96, jj = idx - ocl * 96;
            ws[jj][ocl] = wsrc[wrow0 + (size_t)ocl * wstride + hc0 * 3 + jj];
        }
        __syncthreads();
        for (int c = 0; c < 32; ++c) {
#pragma unroll
            for (int t = 0; t < 3; ++t) {
                float wv8[8];
                *(float4*)&wv8[0] = *(const float4*)&ws[c * 3 + t][wv * 8];
                *(float4*)&wv8[4] = *(const float4*)&ws[c * 3 + t][wv * 8 + 4];
                float xv[4];
#pragma unroll
                for (int si = 0; si < 4; ++si) xv[si] = xs[c][lane + si * 64 + t + 3];
#pragma unroll
                for (int oi = 0; oi < 8; ++oi)
#pragma unroll
                    for (int si = 0; si < 4; ++si)
                        acc[oi][si] += wv8[oi] * xv[si];
            }
        }
    }

    if (!isbias) {
#pragma unroll
        for (int si = 0; si < 4; ++si) {
            int l = lane + si * 64;
            float* op = kh + ((size_t)b * LL + l) * KCL + g * 64 + oc0 + wv * 8;
            *(float4*)(op)     = make_float4(acc[0][si], acc[1][si], acc[2][si], acc[3][si]);
            *(float4*)(op + 4) = make_float4(acc[4][si], acc[5][si], acc[6][si], acc[7][si]);
        }
    } else {
#pragma unroll
        for (int oi = 0; oi < 8; ++oi) {
            float* op = bh + ((size_t)b * 256 + ocb0 + wv * 8 + oi) * LL;
#pragma unroll
            for (int si = 0; si < 4; ++si)
                op[lane + si * 64] = acc[oi][si];
        }
    }
}

// ---------------- fused dilated conv + LVC + gate + residual ----------------
__global__ void __launch_bounds__(512, 4) layer_fused(
    const float* __restrict__ kh, const float* __restrict__ bh,
    const float* __restrict__ w, const float* __restrict__ bias,
    const float* __restrict__ hin, float* __restrict__ hout,
    int layer, int dil) {
    const int l = blockIdx.x, b = blockIdx.y;
    const int tid = threadIdx.x, lane = tid & 63, wv = tid >> 6;
    const int t0 = l * 256;
    __shared__ float xh[32][316];   // 40.4 KB
    __shared__ float ks[KCL];       // 24.6 KB
    __shared__ float ws[96][36];    // 13.8 KB

    const float* hb = hin + (size_t)b * 32 * T;
    for (int idx = tid; idx < 32 * 64; idx += 512) {
        int c = idx >> 6, q = idx & 63;
        float4 v = *(const float4*)(hb + (size_t)c * T + t0 + 4 * q);
        *(float4*)&xh[c][32 + 4 * q] = make_float4(lrelu_f(v.x), lrelu_f(v.y),
                                                   lrelu_f(v.z), lrelu_f(v.w));
    }
    for (int idx = tid; idx < 32 * 60; idx += 512) {
        int c = idx / 60, r = idx - c * 60;
        int jj = (r < 32) ? r : (256 + r);
        int t = t0 + jj - 32;
        xh[c][jj] = (t >= 0 && t < T) ? lrelu_f(hb[(size_t)c * T + t]) : 0.f;
    }
    {
        const float4* kp = (const float4*)(kh + ((size_t)b * LL + l) * KCL);
        float4* kd = (float4*)ks;
        for (int idx = tid; idx < KCL / 4; idx += 512) kd[idx] = kp[idx];
    }
    for (int idx = tid; idx < 3072; idx += 512) {
        int oc = idx / 96, ck = idx - oc * 96;
        ws[ck][oc] = w[oc * 96 + ck];
    }
    __syncthreads();

    // Phase B: dilated conv partials. waves = 4 oc-groups x 2 c-halves.
    const int oc8b = (wv & 3) * 8;
    const int chb  = wv >> 2;
    float p[8][5];
#pragma unroll
    for (int oi = 0; oi < 8; ++oi)
#pragma unroll
        for (int si = 0; si < 5; ++si) p[oi][si] = 0.f;

    for (int c = chb * 16; c < chb * 16 + 16; ++c) {
#pragma unroll
        for (int k = 0; k < 3; ++k) {
            float w8[8];
            *(float4*)&w8[0] = *(const float4*)&ws[c * 3 + k][oc8b];
            *(float4*)&w8[4] = *(const float4*)&ws[c * 3 + k][oc8b + 4];
            float xv[5];
#pragma unroll
            for (int si = 0; si < 5; ++si) {
                int col = lane + si * 64;
                int colc = (col < 258) ? col : 257;
                xv[si] = xh[c][colc + 31 + (k - 1) * dil];
            }
#pragma unroll
            for (int oi = 0; oi < 8; ++oi)
#pragma unroll
                for (int si = 0; si < 5; ++si)
                    p[oi][si] += w8[oi] * xv[si];
        }
    }
    __syncthreads();   // all xh reads done

    // reduction through xh: ch0 writes partial+bias, ch1 adds + lrelu + mask
    if (chb == 0) {
#pragma unroll
        for (int si = 0; si < 5; ++si) {
            int col = lane + si * 64;
            if (col < 258) {
#pragma unroll
                for (int oi = 0; oi < 8; ++oi)
                    xh[oc8b + oi][col + 31] = p[oi][si] + bias[oc8b + oi];
            }
        }
    }
    __syncthreads();
    if (chb == 1) {
#pragma unroll
        for (int si = 0; si < 5; ++si) {
            int col = lane + si * 64;
            if (col < 258) {
                int t = t0 - 1 + col;
                bool tv = (t >= 0 && t < T);
#pragma unroll
                for (int oi = 0; oi < 8; ++oi) {
                    float v = xh[oc8b + oi][col + 31] + p[oi][si];
                    xh[oc8b + oi][col + 31] = tv ? lrelu_f(v) : 0.f;
                }
            }
        }
    }
    __syncthreads();

    // Phase D: LVC (unchanged)
    const int oc8 = (wv & 3) * 8;
    const int sh  = wv >> 2;
    float acc_a[8][2], acc_g[8][2];
#pragma unroll
    for (int oi = 0; oi < 8; ++oi) {
        float ba = bh[((size_t)b * 256 + layer * 64 + oc8 + oi) * LL + l];
        float bg = bh[((size_t)b * 256 + layer * 64 + 32 + oc8 + oi) * LL + l];
#pragma unroll
        for (int si = 0; si < 2; ++si) { acc_a[oi][si] = ba; acc_g[oi][si] = bg; }
    }

    for (int c = 0; c < 32; ++c) {
#pragma unroll
        for (int k = 0; k < 3; ++k) {
            const float* kr = ks + (c * 3 + k) * 64;
            float wa[8], wg[8];
            *(float4*)&wa[0] = *(const float4*)(kr + oc8);
            *(float4*)&wa[4] = *(const float4*)(kr + oc8 + 4);
            *(float4*)&wg[0] = *(const float4*)(kr + 32 + oc8);
            *(float4*)&wg[4] = *(const float4*)(kr + 32 + oc8 + 4);
            float xv2[2];
#pragma unroll
            for (int si = 0; si < 2; ++si) {
                int s = lane + (sh * 2 + si) * 64;
                xv2[si] = xh[c][s + k + 31];
            }
#pragma unroll
            for (int oi = 0; oi < 8; ++oi)
#pragma unroll
                for (int si = 0; si < 2; ++si) {
                    acc_a[oi][si] += wa[oi] * xv2[si];
                    acc_g[oi][si] += wg[oi] * xv2[si];
                }
        }
    }

    // Phase E: gate + residual
#pragma unroll
    for (int oi = 0; oi < 8; ++oi) {
        const float* hip = hin + ((size_t)b * 32 + oc8 + oi) * T + t0;
        float* hop = hout + ((size_t)b * 32 + oc8 + oi) * T + t0;
#pragma unroll
        for (int si = 0; si < 2; ++si) {
            int s = lane + (sh * 2 + si) * 64;
            float a = acc_a[oi][si], g = acc_g[oi][si];
            float sg = 1.f / (1.f + __expf(-a));
            float th = tanhf(g);
            hop[s] = sg * th + hip[s];
        }
    }
}

extern "C" void kernel_launch(void* const* d_in, const int* in_sizes, int n_in,
                              void* d_out, int out_size, void* d_ws, size_t ws_size,
                              hipStream_t stream) {
    const float* hidden  = (const float*)d_in[0];
    const float* spec    = (const float*)d_in[1];
    const float* convt_w = (const float*)d_in[2];
    const float* convt_b = (const float*)d_in[3];
    const float* kp_in_w = (const float*)d_in[4];
    const float* kp_in_b = (const float*)d_in[5];
    const float* rb_w1   = (const float*)d_in[6];
    const float* rb_b1   = (const float*)d_in[7];
    const float* rb_w2   = (const float*)d_in[8];
    const float* rb_b2   = (const float*)d_in[9];
    const float* kern_w  = (const float*)d_in[10];
    const float* kern_b  = (const float*)d_in[11];
    const float* bias_w  = (const float*)d_in[12];
    const float* bias_b  = (const float*)d_in[13];
    const float* lvc_w   = (const float*)d_in[14];
    const float* lvc_b   = (const float*)d_in[15];

    float* wsp = (float*)d_ws;
    float* h_ws     = wsp;                                // B*32*T
    float* kh_layer = h_ws + (size_t)NB * 32 * T;         // B*256*6144 [b][l][m]
    float* bh       = kh_layer + (size_t)NB * LL * KCL;   // B*256*256
    float* kp_h     = bh + (size_t)NB * 256 * LL;         // B*64*256

    float* h0 = (float*)d_out;
    float* h1 = h_ws;

    // 1) merged convt + trunk
    phase1<<<dim3(296), 512, 0, stream>>>(hidden, convt_w, convt_b, h0,
                                          spec, kp_in_w, kp_in_b,
                                          rb_w1, rb_b1, rb_w2, rb_b2, kp_h);

    static const int dil[4] = {1, 3, 9, 27};
    float* hin = h0;
    float* hout = h1;
    for (int layer = 0; layer < 4; ++layer) {
        kern_head<<<dim3(layer == 0 ? 200 : 192, NB), 256, 0, stream>>>(
            kp_h, kern_w, kern_b, bias_w, bias_b, kh_layer, bh, layer);
        layer_fused<<<dim3(LL, NB), 512, 0, stream>>>(
            kh_layer, bh, lvc_w + (size_t)layer * 32 * 32 * 3, lvc_b + layer * 32,
            hin, hout, layer, dil[layer]);
        float* tmp = hin; hin = hout; hout = tmp;
    }
    // after 4 swaps the final output landed in h0 = d_out
}